// Round 1
// baseline (1056.262 us; speedup 1.0000x reference)
//
#include <hip/hip_runtime.h>
#include <hip/hip_bf16.h>
#include <stdint.h>

// Problem constants (reference: N=16384, C_IN=4096, C_OUT=4096, fp32, y = x @ W^T + b)
#define NROWS 16384
#define KDIM  4096
#define COUT  4096

typedef float f32x4 __attribute__((ext_vector_type(4)));
typedef __bf16 bf16x8 __attribute__((ext_vector_type(8)));

// ---------------------------------------------------------------------------
// fp32 -> bf16 (RNE) converter, 8 elements/thread, float4-in / uint4-out
// ---------------------------------------------------------------------------
__device__ __forceinline__ unsigned pack_bf16x2(float x, float y) {
    unsigned a = __builtin_bit_cast(unsigned, x);
    unsigned b = __builtin_bit_cast(unsigned, y);
    a = (a + 0x7fffu + ((a >> 16) & 1u)) >> 16;   // round-to-nearest-even
    b = (b + 0x7fffu + ((b >> 16) & 1u)) >> 16;
    return a | (b << 16);
}

__global__ __launch_bounds__(256) void cvt_f32_to_bf16(
    const float* __restrict__ in, uint32_t* __restrict__ out, long long n8) {
    long long i = (long long)blockIdx.x * blockDim.x + threadIdx.x;
    if (i >= n8) return;
    const float4* p = reinterpret_cast<const float4*>(in) + i * 2;
    float4 a = p[0];
    float4 b = p[1];
    uint4 o;
    o.x = pack_bf16x2(a.x, a.y);
    o.y = pack_bf16x2(a.z, a.w);
    o.z = pack_bf16x2(b.x, b.y);
    o.w = pack_bf16x2(b.z, b.w);
    reinterpret_cast<uint4*>(out)[i] = o;
}

// ---------------------------------------------------------------------------
// Async global->LDS, 16B per lane. LDS dest is wave-uniform base + lane*16.
// ---------------------------------------------------------------------------
__device__ __forceinline__ void async16(const void* g, void* l) {
    __builtin_amdgcn_global_load_lds(
        reinterpret_cast<const unsigned __attribute__((address_space(1)))*>(
            reinterpret_cast<uintptr_t>(g)),
        reinterpret_cast<unsigned __attribute__((address_space(3)))*>(
            reinterpret_cast<uintptr_t>(l)),   // low 32 bits = LDS offset
        16, 0, 0);
}

// ---------------------------------------------------------------------------
// C[m][n] = sum_k A[m][k] * B[n][k] + bias[n]   (A: NROWS x K, B: COUT x K, bf16)
// 128x128 block tile, BK=32, 256 threads = 4 waves, each wave 64x64 (4x4 MFMA
// tiles of 16x16x32 bf16). m97-ladder structure: global_load_lds width=16,
// unpadded 32-elem LDS rows, 2-barrier K-loop.
// __launch_bounds__(256,3): 3 waves/EU -> VGPR cap ~170 (m97 used 164).
// ---------------------------------------------------------------------------
__global__ __launch_bounds__(256, 3) void gemm_bt_bf16(
    const short* __restrict__ A,     // NROWS x KDIM (bf16 bits)
    const short* __restrict__ B,     // COUT  x KDIM (bf16 bits)
    const float* __restrict__ bias,  // COUT
    float* __restrict__ C) {         // NROWS x COUT
    __shared__ alignas(16) short As[128 * 32];
    __shared__ alignas(16) short Bs[128 * 32];

    const int tid  = threadIdx.x;
    const int wave = tid >> 6;
    const int lane = tid & 63;

    const int block_m = blockIdx.y * 128;   // row block in NROWS
    const int block_n = blockIdx.x * 128;   // col block in COUT

    // --- staging addressing -------------------------------------------------
    // Wave w, chunk c covers LDS rows [c*64 + w*16, +16); lane L writes
    // row c*64 + w*16 + L/4, k-offset (L%4)*8 -> matches base + L*16 bytes.
    const int srow = wave * 16 + (lane >> 2);
    const int scol = (lane & 3) * 8;
    const short* ag = A + (size_t)(block_m + srow) * KDIM + scol;
    const short* bg = B + (size_t)(block_n + srow) * KDIM + scol;
    short* as_dst = As + wave * 512;   // elements; chunk1 at +2048 (rows +64)
    short* bs_dst = Bs + wave * 512;

    // --- fragment addressing ------------------------------------------------
    const int wm = (wave & 1) * 64;    // wave's 64x64 quadrant
    const int wn = (wave >> 1) * 64;
    const int fr = lane & 15;          // A/B frag: element row = lane&15
    const int fk = (lane >> 4) * 8;    // k = quad*8 + j  (ds_read_b128)

    f32x4 acc[4][4] = {};

    for (int k0 = 0; k0 < KDIM; k0 += 32) {
        async16(ag, as_dst);
        async16(ag + (size_t)64 * KDIM, as_dst + 2048);
        async16(bg, bs_dst);
        async16(bg + (size_t)64 * KDIM, bs_dst + 2048);
        ag += 32;
        bg += 32;
        __syncthreads();   // compiler drains vmcnt(0) before s_barrier

        bf16x8 a_frag[4], b_frag[4];
#pragma unroll
        for (int i = 0; i < 4; ++i)
            a_frag[i] = *reinterpret_cast<const bf16x8*>(
                As + (wm + i * 16 + fr) * 32 + fk);
#pragma unroll
        for (int j = 0; j < 4; ++j)
            b_frag[j] = *reinterpret_cast<const bf16x8*>(
                Bs + (wn + j * 16 + fr) * 32 + fk);

#pragma unroll
        for (int i = 0; i < 4; ++i)
#pragma unroll
            for (int j = 0; j < 4; ++j)
                acc[i][j] = __builtin_amdgcn_mfma_f32_16x16x32_bf16(
                    a_frag[i], b_frag[j], acc[i][j], 0, 0, 0);

        __syncthreads();   // protect LDS before next iteration's staging
    }

    // --- epilogue: C/D layout col=lane&15, row=(lane>>4)*4+reg (m89/m91) ----
    const int cm = block_m + wm + (lane >> 4) * 4;
    const int cn = block_n + wn + (lane & 15);
#pragma unroll
    for (int j = 0; j < 4; ++j) {
        const float bj = bias[cn + j * 16];
#pragma unroll
        for (int i = 0; i < 4; ++i) {
#pragma unroll
            for (int r = 0; r < 4; ++r) {
                C[(size_t)(cm + i * 16 + r) * COUT + (cn + j * 16)] =
                    acc[i][j][r] + bj;
            }
        }
    }
}

// ---------------------------------------------------------------------------
extern "C" void kernel_launch(void* const* d_in, const int* in_sizes, int n_in,
                              void* d_out, int out_size, void* d_ws, size_t ws_size,
                              hipStream_t stream) {
    const float* x    = (const float*)d_in[0];   // NROWS x KDIM
    const float* w    = (const float*)d_in[1];   // COUT  x KDIM
    const float* bias = (const float*)d_in[2];   // COUT
    float* out = (float*)d_out;

    // workspace layout: xb (134.2 MB) | wb (33.6 MB)
    short* xb = (short*)d_ws;
    short* wb = xb + (size_t)NROWS * KDIM;

    const long long n8_x = (long long)NROWS * KDIM / 8;   // 8388608
    const long long n8_w = (long long)COUT * KDIM / 8;    // 2097152

    cvt_f32_to_bf16<<<(int)(n8_x / 256), 256, 0, stream>>>(x, (uint32_t*)xb, n8_x);
    cvt_f32_to_bf16<<<(int)(n8_w / 256), 256, 0, stream>>>(w, (uint32_t*)wb, n8_w);

    dim3 grid(COUT / 128, NROWS / 128);   // (32, 128) = 4096 blocks
    gemm_bt_bf16<<<grid, 256, 0, stream>>>(xb, wb, bias, out);
}

// Round 2
// 1050.206 us; speedup vs baseline: 1.0058x; 1.0058x over previous
//
#include <hip/hip_runtime.h>
#include <hip/hip_bf16.h>
#include <stdint.h>

// Problem constants (reference: N=16384, C_IN=4096, C_OUT=4096, fp32, y = x @ W^T + b)
#define NROWS 16384
#define KDIM  4096
#define COUT  4096

typedef float f32x4 __attribute__((ext_vector_type(4)));
typedef __bf16 bf16x8 __attribute__((ext_vector_type(8)));

// ---------------------------------------------------------------------------
// fp32 -> bf16 (RNE) converter, 4 elements/thread, fully coalesced:
// lane i loads float4 at [i], stores uint2 at [i] — 16B-in/8B-out contiguous.
// ---------------------------------------------------------------------------
__device__ __forceinline__ unsigned pack_bf16x2(float x, float y) {
    unsigned a = __builtin_bit_cast(unsigned, x);
    unsigned b = __builtin_bit_cast(unsigned, y);
    a = (a + 0x7fffu + ((a >> 16) & 1u)) >> 16;   // round-to-nearest-even
    b = (b + 0x7fffu + ((b >> 16) & 1u)) >> 16;
    return a | (b << 16);
}

__global__ __launch_bounds__(256) void cvt_f32_to_bf16(
    const float4* __restrict__ in, uint2* __restrict__ out, int n4) {
    int i = blockIdx.x * blockDim.x + threadIdx.x;
    if (i >= n4) return;
    float4 a = in[i];
    uint2 o;
    o.x = pack_bf16x2(a.x, a.y);
    o.y = pack_bf16x2(a.z, a.w);
    out[i] = o;
}

// ---------------------------------------------------------------------------
// Async global->LDS, 16B per lane. LDS dest is wave-uniform base + lane*16.
// ---------------------------------------------------------------------------
__device__ __forceinline__ void async16(const void* g, void* l) {
    __builtin_amdgcn_global_load_lds(
        reinterpret_cast<const unsigned __attribute__((address_space(1)))*>(
            reinterpret_cast<uintptr_t>(g)),
        reinterpret_cast<unsigned __attribute__((address_space(3)))*>(
            reinterpret_cast<uintptr_t>(l)),   // low 32 bits = LDS offset
        16, 0, 0);
}

// ---------------------------------------------------------------------------
// C[m][n] = sum_k A[m][k] * B[n][k] + bias[n]   (A: NROWS x K, B: COUT x K, bf16)
// 128x128 block tile, BK=32, 256 threads = 4 waves, each wave 64x64 (4x4 MFMA
// tiles of 16x16x32 bf16).
//
// LDS bank-conflict swizzle (R1): a tile row is 4 chunks of 16B. Chunk c of
// row r is stored at slot (c ^ ((r>>1)&3)). Fragment reads then spread each
// 16-lane phase across all 8 four-bank groups at 2 lanes each (2-way = free,
// m136), vs 8-way conflict unswizzled (R1 counter: 6.7e7 conflict cycles).
// global_load_lds dst stays base+lane*16; lanes fetch the permuted global
// chunk instead.
// ---------------------------------------------------------------------------
__global__ __launch_bounds__(256, 3) void gemm_bt_bf16(
    const short* __restrict__ A,     // NROWS x KDIM (bf16 bits)
    const short* __restrict__ B,     // COUT  x KDIM (bf16 bits)
    const float* __restrict__ bias,  // COUT
    float* __restrict__ C) {         // NROWS x COUT
    __shared__ alignas(16) short As[128 * 32];
    __shared__ alignas(16) short Bs[128 * 32];

    const int tid  = threadIdx.x;
    const int wave = tid >> 6;
    const int lane = tid & 63;

    const int block_m = blockIdx.y * 128;   // row block in NROWS
    const int block_n = blockIdx.x * 128;   // col block in COUT

    // --- staging addressing (with XOR swizzle) ------------------------------
    // Wave w, chunk blk c covers LDS rows [c*64 + w*16, +16); lane L writes
    // slot (row = w*16 + L/4, pos = L&3), which holds global chunk
    // (L&3) ^ ((L>>3)&3)  [since ((row)>>1)&3 == (L>>3)&3 for 16-aligned bases].
    const int srow = wave * 16 + (lane >> 2);
    const int scol = (((lane & 3) ^ ((lane >> 3) & 3)) * 8);
    const short* ag = A + (size_t)(block_m + srow) * KDIM + scol;
    const short* bg = B + (size_t)(block_n + srow) * KDIM + scol;
    short* as_dst = As + wave * 512;   // elements; chunk1 at +2048 (rows +64)
    short* bs_dst = Bs + wave * 512;

    // --- fragment addressing ------------------------------------------------
    const int wm = (wave & 1) * 64;    // wave's 64x64 quadrant
    const int wn = (wave >> 1) * 64;
    const int fr = lane & 15;          // A/B frag: element row = lane&15
    const int fq = lane >> 4;          // k-chunk index 0..3
    // swizzled chunk slot for (row ≡ fr mod 16, chunk fq):
    const int fslot = (fq ^ ((fr >> 1) & 3)) * 8;   // in shorts

    f32x4 acc[4][4] = {};

    for (int k0 = 0; k0 < KDIM; k0 += 32) {
        async16(ag, as_dst);
        async16(ag + (size_t)64 * KDIM, as_dst + 2048);
        async16(bg, bs_dst);
        async16(bg + (size_t)64 * KDIM, bs_dst + 2048);
        ag += 32;
        bg += 32;
        __syncthreads();   // compiler drains vmcnt(0) before s_barrier

        bf16x8 a_frag[4], b_frag[4];
#pragma unroll
        for (int i = 0; i < 4; ++i)
            a_frag[i] = *reinterpret_cast<const bf16x8*>(
                As + (wm + i * 16 + fr) * 32 + fslot);
#pragma unroll
        for (int j = 0; j < 4; ++j)
            b_frag[j] = *reinterpret_cast<const bf16x8*>(
                Bs + (wn + j * 16 + fr) * 32 + fslot);

#pragma unroll
        for (int i = 0; i < 4; ++i)
#pragma unroll
            for (int j = 0; j < 4; ++j)
                acc[i][j] = __builtin_amdgcn_mfma_f32_16x16x32_bf16(
                    a_frag[i], b_frag[j], acc[i][j], 0, 0, 0);

        __syncthreads();   // protect LDS before next iteration's staging
    }

    // --- epilogue: C/D layout col=lane&15, row=(lane>>4)*4+reg (m89/m91) ----
    const int cm = block_m + wm + (lane >> 4) * 4;
    const int cn = block_n + wn + (lane & 15);
#pragma unroll
    for (int j = 0; j < 4; ++j) {
        const float bj = bias[cn + j * 16];
#pragma unroll
        for (int i = 0; i < 4; ++i) {
#pragma unroll
            for (int r = 0; r < 4; ++r) {
                C[(size_t)(cm + i * 16 + r) * COUT + (cn + j * 16)] =
                    acc[i][j][r] + bj;
            }
        }
    }
}

// ---------------------------------------------------------------------------
extern "C" void kernel_launch(void* const* d_in, const int* in_sizes, int n_in,
                              void* d_out, int out_size, void* d_ws, size_t ws_size,
                              hipStream_t stream) {
    const float* x    = (const float*)d_in[0];   // NROWS x KDIM
    const float* w    = (const float*)d_in[1];   // COUT  x KDIM
    const float* bias = (const float*)d_in[2];   // COUT
    float* out = (float*)d_out;

    // workspace layout: xb (134.2 MB) | wb (33.6 MB)
    short* xb = (short*)d_ws;
    short* wb = xb + (size_t)NROWS * KDIM;

    const int n4_x = NROWS * (KDIM / 4);   // 16777216
    const int n4_w = COUT  * (KDIM / 4);   // 4194304

    cvt_f32_to_bf16<<<n4_x / 256, 256, 0, stream>>>(
        (const float4*)x, (uint2*)xb, n4_x);
    cvt_f32_to_bf16<<<n4_w / 256, 256, 0, stream>>>(
        (const float4*)w, (uint2*)wb, n4_w);

    dim3 grid(COUT / 128, NROWS / 128);   // (32, 128) = 4096 blocks
    gemm_bt_bf16<<<grid, 256, 0, stream>>>(xb, wb, bias, out);
}